// Round 6
// baseline (272.668 us; speedup 1.0000x reference)
//
#include <hip/hip_runtime.h>

typedef unsigned short u16;
typedef __bf16 bf16x8 __attribute__((ext_vector_type(8)));
typedef float f32x4 __attribute__((ext_vector_type(4)));
typedef unsigned short u16x8 __attribute__((ext_vector_type(8)));

#define Bq 4
#define Dq 768
#define Lq 4096
#define Mq (Lq * Bq)   // 16384
#define NKq 24         // K=768 / BK=32

__device__ __forceinline__ u16 f2bf(float f) {
    unsigned int u = __builtin_bit_cast(unsigned int, f);
    u += 0x7fffu + ((u >> 16) & 1u);   // RNE
    return (u16)(u >> 16);
}

__device__ __forceinline__ float bf2f(u16 h) {
    return __builtin_bit_cast(float, (unsigned int)h << 16);
}

__device__ __forceinline__ void async16(const void* g, void* l) {
    __builtin_amdgcn_global_load_lds(
        (const __attribute__((address_space(1))) unsigned int*)(unsigned long long)g,
        (__attribute__((address_space(3))) unsigned int*)(unsigned int)(unsigned long long)l,
        16, 0, 0);
}

// ---- prep: fp32 weights -> bf16, zero the 4 pad rows of Vpad/Gpad ----
__global__ __launch_bounds__(256) void prep_kernel(
    const float* __restrict__ Wih, const float* __restrict__ Whh,
    u16* __restrict__ Wihb, u16* __restrict__ Whhb,
    u16* __restrict__ Vpad, u16* __restrict__ Gpad) {
    int i = blockIdx.x * 256 + threadIdx.x;
    if (i < Dq * Dq) {
        Wihb[i] = f2bf(Wih[i]);
        Whhb[i] = f2bf(Whh[i]);
    }
    if (i < Bq * Dq) { Vpad[i] = 0; Gpad[i] = 0; }
}

// ---- transpose x [B,D,L] fp32 -> Xt [(l*B+b), d] bf16 ----
__global__ __launch_bounds__(256) void transpose_kernel(
    const float* __restrict__ x, u16* __restrict__ Xt) {
    __shared__ u16 tile[64][66];
    int b = blockIdx.z, d0 = blockIdx.y * 64, l0 = blockIdx.x * 64;
    int tx = threadIdx.x & 63, ty = threadIdx.x >> 6;
    const float* xp = x + ((size_t)b * Dq + d0) * Lq + l0;
#pragma unroll
    for (int i = 0; i < 16; ++i) {
        int r = i * 4 + ty;
        tile[r][tx] = f2bf(xp[(size_t)r * Lq + tx]);
    }
    __syncthreads();
    u16* xt = Xt + ((size_t)l0 * Bq + b) * Dq + d0;
#pragma unroll
    for (int i = 0; i < 16; ++i) {
        int c = i * 4 + ty;
        xt[(size_t)c * Bq * Dq + tx] = tile[tx][c];
    }
}

// ---- K=768 GEMM, barrier-free K-loop ----
// Block: 256x64 tile (4 waves x 64 m-rows), W n-panel persisted in LDS in two
// k-phases (12 chunks x [64 rows][32 k] = 48 KB each). A fragments stream from
// global directly into registers (ping-pong, 1-iter prefetch). The K-loop has
// NO barriers; only the phase switch (2 barriers) and epilogue sync.
// XCD swizzle: g = blk%64 (m-group), nb = blk/64 -> all 12 n-blocks of a group
// share an XCD (blk%8 == g%8), so A re-reads are XCD-L2-resident (~1.6 MB).
// MODE 0 (pass A): Ub = acc + bih + bhh (bf16); Vpad = relu(Ub) at +4 rows
// MODE 1 (pass B): Gpad = relu(Ub + acc) at +4 rows
// MODE 2 (pass C): Eout[B,D,L] = relu(Ub + acc), transposed via LDS, bf16
template <int MODE>
__global__ __launch_bounds__(256, 3) void gemm_kernel(
    const u16* __restrict__ A, const u16* __restrict__ W,
    const u16* __restrict__ Ub_in, u16* __restrict__ Out0, u16* __restrict__ Out1,
    const float* __restrict__ bih, const float* __restrict__ bhh) {
    __shared__ __align__(16) char smem[49152];
    u16* Wp = (u16*)smem;   // 12 chunks x [64][32] u16

    int tid = threadIdx.x;
    int wave = tid >> 6, lane = tid & 63;
    int lr = lane & 15, lq = lane >> 4;
    int g = blockIdx.x & 63, nb = blockIdx.x >> 6;
    int m0 = g * 256, n0 = nb * 64;
    int mw = m0 + wave * 64;

    // W staging: wave stages 3 chunks; per async16 lane -> (row=lane>>2,
    // seg=lane&3) => LDS dst == uniform base + lane*16B (HW requirement)
    const u16* wrow = W + (size_t)(n0 + (lane >> 2)) * Dq + (lane & 3) * 8;
    auto stageW = [&](int phase) {
#pragma unroll
        for (int t = 0; t < 3; ++t) {
            int c = wave * 3 + t;
            const u16* src = wrow + phase * 384 + c * 32;
            u16* dst = Wp + c * 2048;
#pragma unroll
            for (int rg = 0; rg < 4; ++rg)
                async16(src + (size_t)rg * 16 * Dq, dst + rg * 512);
        }
    };

    // A: lane (m = lr, k-half = lq) reads 16B contiguous -> MFMA A-operand
    const u16* arow = A + (size_t)(mw + lr) * Dq + lq * 8;
    auto loadA = [&](bf16x8 (&dst)[4], int kk) {
#pragma unroll
        for (int t = 0; t < 4; ++t)
            dst[t] = *(const bf16x8*)(arow + (size_t)t * 16 * Dq + kk);
    };

    f32x4 acc[4][4];
#pragma unroll
    for (int i = 0; i < 4; ++i)
#pragma unroll
        for (int j = 0; j < 4; ++j) acc[i][j] = f32x4{0.f, 0.f, 0.f, 0.f};

    bf16x8 a0[4], a1[4];
    stageW(0);
    loadA(a0, 0);
    __syncthreads();   // W phase-0 staged (+ a0 arrived)

    auto kbody = [&](int j, bf16x8 (&cur)[4], bf16x8 (&nxt)[4]) {
        int kk = j * 32;
        if (j + 1 < NKq) loadA(nxt, kk + 32);   // register prefetch, 1-iter lead
        int cc = (j >= 12) ? (j - 12) : j;
        bf16x8 bfr[4];
#pragma unroll
        for (int nt = 0; nt < 4; ++nt)
            bfr[nt] = *(const bf16x8*)(Wp + cc * 2048 + (nt * 16 + lr) * 32 + lq * 8);
#pragma unroll
        for (int mt = 0; mt < 4; ++mt)
#pragma unroll
            for (int nt = 0; nt < 4; ++nt)
                acc[mt][nt] = __builtin_amdgcn_mfma_f32_16x16x32_bf16(
                    cur[mt], bfr[nt], acc[mt][nt], 0, 0, 0);
    };

    for (int jj = 0; jj < NKq; jj += 2) {
        if (jj == 12) {            // k-phase switch: the only K-loop barriers
            __syncthreads();       // all waves done reading phase-0 panel
            stageW(1);
            __syncthreads();       // phase-1 panel staged
        }
        kbody(jj, a0, a1);
        kbody(jj + 1, a1, a0);
    }
    __syncthreads();   // drain before epilogue smem reuse

    // ---- epilogue ----  C/D layout: col = lane&15, row = (lane>>4)*4 + r
    u16* tb = (u16*)smem;   // [256][72] bf16 (36.9 KB)

    if constexpr (MODE == 0) {
#pragma unroll
        for (int nt = 0; nt < 4; ++nt) {
            int cl = nt * 16 + lr;
            float bsum = bih[n0 + cl] + bhh[n0 + cl];
#pragma unroll
            for (int mt = 0; mt < 4; ++mt) {
                int rl = wave * 64 + mt * 16 + lq * 4;
                f32x4 v = acc[mt][nt];
#pragma unroll
                for (int r = 0; r < 4; ++r)
                    tb[(rl + r) * 72 + cl] = f2bf(v[r] + bsum);
            }
        }
        __syncthreads();
#pragma unroll
        for (int p = 0; p < 8; ++p) {
            int gi = tid + p * 256;          // 2048 chunks of 8 u16
            int row = gi >> 3, c8 = gi & 7;
            u16x8 hv = *(const u16x8*)(tb + row * 72 + c8 * 8);
            *(u16x8*)(Out0 + (size_t)(m0 + row) * Dq + n0 + c8 * 8) = hv;       // Ub
            u16x8 hr;
#pragma unroll
            for (int k = 0; k < 8; ++k) hr[k] = (hv[k] & 0x8000u) ? (u16)0 : hv[k];
            *(u16x8*)(Out1 + (size_t)(m0 + row + Bq) * Dq + n0 + c8 * 8) = hr;  // Vpad
        }
    } else if constexpr (MODE == 1) {
#pragma unroll
        for (int p = 0; p < 8; ++p) {
            int gi = tid + p * 256;
            int row = gi >> 3, c8 = gi & 7;
            *(u16x8*)(tb + row * 72 + c8 * 8) =
                *(const u16x8*)(Ub_in + (size_t)(m0 + row) * Dq + n0 + c8 * 8);
        }
        __syncthreads();
#pragma unroll
        for (int nt = 0; nt < 4; ++nt) {
            int cl = nt * 16 + lr;
#pragma unroll
            for (int mt = 0; mt < 4; ++mt) {
                int rl = wave * 64 + mt * 16 + lq * 4;
                f32x4 v = acc[mt][nt];
#pragma unroll
                for (int r = 0; r < 4; ++r) {
                    float gg = fmaxf(v[r] + bf2f(tb[(rl + r) * 72 + cl]), 0.f);
                    tb[(rl + r) * 72 + cl] = f2bf(gg);   // cell owned by this thread
                }
            }
        }
        __syncthreads();
#pragma unroll
        for (int p = 0; p < 8; ++p) {
            int gi = tid + p * 256;
            int row = gi >> 3, c8 = gi & 7;
            u16x8 hv = *(const u16x8*)(tb + row * 72 + c8 * 8);
            *(u16x8*)(Out0 + (size_t)(m0 + row + Bq) * Dq + n0 + c8 * 8) = hv;  // Gpad
        }
    } else {
        // MODE 2: fold Ub into acc, then transpose to [B,D,L] bf16 via LDS
#pragma unroll
        for (int p = 0; p < 8; ++p) {
            int gi = tid + p * 256;
            int row = gi >> 3, c8 = gi & 7;
            *(u16x8*)(tb + row * 72 + c8 * 8) =
                *(const u16x8*)(Ub_in + (size_t)(m0 + row) * Dq + n0 + c8 * 8);
        }
        __syncthreads();
#pragma unroll
        for (int nt = 0; nt < 4; ++nt) {
            int cl = nt * 16 + lr;
#pragma unroll
            for (int mt = 0; mt < 4; ++mt) {
                int rl = wave * 64 + mt * 16 + lq * 4;
#pragma unroll
                for (int r = 0; r < 4; ++r)
                    acc[mt][nt][r] = fmaxf(acc[mt][nt][r] + bf2f(tb[(rl + r) * 72 + cl]), 0.f);
            }
        }
        __syncthreads();   // tb reads done; reuse smem as per-wave epw
        float* epw = (float*)smem + wave * (64 * 17);
        int l0w = g * 64 + wave * 16;   // wave covers 16 l values, 4 b values
#pragma unroll
        for (int nt = 0; nt < 4; ++nt) {
#pragma unroll
            for (int mt = 0; mt < 4; ++mt) {
                int lmb = mt * 16 + lq * 4;
                f32x4 v = acc[mt][nt];
#pragma unroll
                for (int r = 0; r < 4; ++r)
                    epw[(lmb + r) * 17 + lr] = v[r];
            }
            // wave-private region: in-wave ds ordering via lgkmcnt (no barrier)
            int bb = lane >> 4, cc = lane & 15;
            int gnc = n0 + nt * 16 + cc;
            float vals[16];
#pragma unroll
            for (int ll = 0; ll < 16; ++ll)
                vals[ll] = epw[(ll * 4 + bb) * 17 + cc];
            u16* dst = Out0 + (size_t)bb * (Dq * Lq) + (size_t)gnc * Lq + l0w;
            u16x8 h0, h1;
#pragma unroll
            for (int k = 0; k < 8; ++k) { h0[k] = f2bf(vals[k]); h1[k] = f2bf(vals[8 + k]); }
            *(u16x8*)dst = h0;
            *(u16x8*)(dst + 8) = h1;
        }
    }
}

// ---- fused residual + LayerNorm over L (E is bf16 [B,D,L]) ----
__global__ __launch_bounds__(256) void ln_kernel(
    const u16* __restrict__ E, const float* __restrict__ x,
    const float* __restrict__ gamma, const float* __restrict__ beta,
    float* __restrict__ out) {
    __shared__ float red[2][4];
    size_t row = blockIdx.x;
    const u16x8* e8 = (const u16x8*)(E + row * Lq);
    const float* xr = x + row * Lq;
    float* o = out + row * Lq;
    int t = threadIdx.x;
    float z[16];
    float s = 0.f, sq = 0.f;
#pragma unroll
    for (int i = 0; i < 2; ++i) {
        int c = i * 256 + t;
        u16x8 ev = e8[c];
        f32x4 xv0 = *(const f32x4*)(xr + c * 8);
        f32x4 xv1 = *(const f32x4*)(xr + c * 8 + 4);
#pragma unroll
        for (int j = 0; j < 4; ++j) {
            float z0 = bf2f(ev[j]) + xv0[j];
            float z1 = bf2f(ev[4 + j]) + xv1[j];
            z[i * 8 + j] = z0;
            z[i * 8 + 4 + j] = z1;
            s += z0 + z1;
            sq += z0 * z0 + z1 * z1;
        }
    }
#pragma unroll
    for (int off = 32; off > 0; off >>= 1) {
        s += __shfl_down(s, off);
        sq += __shfl_down(sq, off);
    }
    int wave = t >> 6, lane = t & 63;
    if (lane == 0) { red[0][wave] = s; red[1][wave] = sq; }
    __syncthreads();
    s = red[0][0] + red[0][1] + red[0][2] + red[0][3];
    sq = red[1][0] + red[1][1] + red[1][2] + red[1][3];
    float mean = s * (1.f / Lq);
    float var = sq * (1.f / Lq) - mean * mean;
    float rstd = rsqrtf(var + 1e-12f);
#pragma unroll
    for (int i = 0; i < 2; ++i) {
        int c = i * 256 + t;
#pragma unroll
        for (int h = 0; h < 2; ++h) {
            int idx = c * 8 + h * 4;
            f32x4 gv = *(const f32x4*)(gamma + idx);
            f32x4 bv = *(const f32x4*)(beta + idx);
            f32x4 ov;
#pragma unroll
            for (int j = 0; j < 4; ++j)
                ov[j] = (z[i * 8 + h * 4 + j] - mean) * rstd * gv[j] + bv[j];
            *(f32x4*)(o + idx) = ov;
        }
    }
}

extern "C" void kernel_launch(void* const* d_in, const int* in_sizes, int n_in,
                              void* d_out, int out_size, void* d_ws, size_t ws_size,
                              hipStream_t stream) {
    const float* x     = (const float*)d_in[0];
    const float* Wih   = (const float*)d_in[1];
    const float* Whh   = (const float*)d_in[2];
    const float* bih   = (const float*)d_in[3];
    const float* bhh   = (const float*)d_in[4];
    const float* gamma = (const float*)d_in[5];
    const float* beta  = (const float*)d_in[6];
    float* out = (float*)d_out;

    char* ws = (char*)d_ws;
    u16* Xt    = (u16*)ws;   ws += (size_t)Mq * Dq * 2;          // 25.2 MB
    u16* Wihb  = (u16*)ws;   ws += (size_t)Dq * Dq * 2;
    u16* Whhb  = (u16*)ws;   ws += (size_t)Dq * Dq * 2;
    u16* Ub    = (u16*)ws;   ws += (size_t)Mq * Dq * 2;          // 25.2 MB
    u16* Vpad  = (u16*)ws;   ws += (size_t)(Mq + Bq) * Dq * 2;   // 25.2 MB
    u16* Gpad  = (u16*)ws;   ws += (size_t)(Mq + Bq) * Dq * 2;   // 25.2 MB
    u16* Eout  = (u16*)ws;   ws += (size_t)Mq * Dq * 2;          // 25.2 MB

    prep_kernel<<<dim3((Dq * Dq + 255) / 256), 256, 0, stream>>>(
        Wih, Whh, Wihb, Whhb, Vpad, Gpad);
    transpose_kernel<<<dim3(Lq / 64, Dq / 64, Bq), 256, 0, stream>>>(x, Xt);

    dim3 ggrid(768);   // 64 m-groups x 12 n-blocks; XCD = blk%8 = m-group%8
    // pass A: Ub = X@Wih^T + bih + bhh ; Vpad = relu(Ub) shifted +4 rows
    gemm_kernel<0><<<ggrid, 256, 0, stream>>>(Xt,   Wihb, nullptr, Ub,  Vpad, bih, bhh);
    // pass B: Gpad = relu(Ub + Vprev@Whh^T) shifted +4 rows
    gemm_kernel<1><<<ggrid, 256, 0, stream>>>(Vpad, Whhb, Ub, Gpad, nullptr, bih, bhh);
    // pass C: Eout[B,D,L] = relu(Ub + Gprev@Whh^T), transposed, bf16
    gemm_kernel<2><<<ggrid, 256, 0, stream>>>(Gpad, Whhb, Ub, Eout, nullptr, bih, bhh);

    ln_kernel<<<dim3(Bq * Dq), 256, 0, stream>>>(Eout, x, gamma, beta, out);
}